// Round 6
// baseline (595.049 us; speedup 1.0000x reference)
//
#include <hip/hip_runtime.h>
#include <hip/hip_bf16.h>
#include <math.h>

// Dims (fixed by the problem)
#define Bd 32
#define Sd 256
#define Ld 24
#define Ed 300
#define Hd 256
#define Td 16
#define Dd 256
#define EP 320    // E padded to multiple of 32

using short8 = __attribute__((ext_vector_type(8))) short;
using f32x4  = __attribute__((ext_vector_type(4))) float;

// fast transcendentals (v_exp_f32 path; saturate correctly at +-inf)
__device__ __forceinline__ float fsigm(float x) { return 1.f / (1.f + __expf(-x)); }
__device__ __forceinline__ float ftanh(float x) {
  float e = __expf(2.f * x);
  return 1.f - 2.f / (e + 1.f);
}

// ---------------------------------------------------------------------------
// 1. FUSED sentence means + GRU-weight prep + bias concat. block 320.
// blocks [0,8192): A_pad[r][k] = bf16(mean_w emb[word_ids[r][w]][k])
// blocks [8192,10962): prep (wih pad f+b, whh f2bf f+b, bias_cat[1536])
__global__ void sentprep_kernel(const int* __restrict__ wids,
                                const float* __restrict__ emb,
                                __hip_bfloat16* __restrict__ apad,
                                const float* __restrict__ wih_f, const float* __restrict__ wih_b,
                                const float* __restrict__ whh_f, const float* __restrict__ whh_b,
                                __hip_bfloat16* __restrict__ wpadf, __hip_bfloat16* __restrict__ wpadb,
                                __hip_bfloat16* __restrict__ whhbf_f, __hip_bfloat16* __restrict__ whhbf_b,
                                const float* __restrict__ bih_f, const float* __restrict__ bih_b,
                                float* __restrict__ bias_cat) {
  const int blk = blockIdx.x;
  const int tid = threadIdx.x;
  if (blk < 8192) {
    __shared__ int ids[Ld];
    if (tid < Ld) ids[tid] = wids[blk * Ld + tid];
    __syncthreads();
    float acc = 0.f;
    if (tid < Ed) {
#pragma unroll
      for (int w = 0; w < Ld; ++w) acc += emb[(size_t)ids[w] * Ed + tid];
      acc *= (1.f / 24.f);
    }
    apad[blk * EP + tid] = __float2bfloat16(tid < Ed ? acc : 0.f);
    return;
  }
  const int i = (blk - 8192) * 320 + tid;
  const int PW = 768 * EP;     // 245760
  const int WH = 768 * Hd;     // 196608
  if (i < 2 * PW) {
    const float* src = (i < PW) ? wih_f : wih_b;
    __hip_bfloat16* dst = (i < PW) ? wpadf : wpadb;
    int j = (i < PW) ? i : i - PW;
    int n = j / EP, k = j % EP;
    dst[j] = __float2bfloat16(k < Ed ? src[n * Ed + k] : 0.f);
  } else if (i < 2 * PW + 2 * WH) {
    int j = i - 2 * PW;
    const float* src = (j < WH) ? whh_f : whh_b;
    __hip_bfloat16* dst = (j < WH) ? whhbf_f : whhbf_b;
    int k = (j < WH) ? j : j - WH;
    dst[k] = __float2bfloat16(src[k]);
  } else if (i < 2 * PW + 2 * WH + 1536) {
    int j = i - 2 * PW - 2 * WH;
    bias_cat[j] = (j < 768) ? bih_f[j] : bih_b[j - 768];
  }
}

// ---------------------------------------------------------------------------
// 2. MFMA GEMM 128-tile (exact dims: M%128==0, N%128==0, K%32==0).
// 4 waves, each a 64x64 quadrant; 16 MFMAs per 8 ds_read_b128 per K-step.
// LDS rows padded to 40 shorts (80B stride): fragment reads tile all 32
// banks at the free 2-way level.
__global__ __launch_bounds__(256) void gemm128_xwt_kernel(
    const __hip_bfloat16* __restrict__ A, int lda,
    const __hip_bfloat16* __restrict__ W, int ldw,
    float* __restrict__ C, int ldc,
    int M, int N, int K,
    const float* __restrict__ bias) {
  __shared__ unsigned short la[128][40];
  __shared__ unsigned short lb[128][40];
  const int tid = threadIdx.x;
  const int m0 = blockIdx.x * 128, n0 = blockIdx.y * 128;
  const int lane = tid & 63, wid = tid >> 6;
  const int wm = (wid >> 1) * 64, wn = (wid & 1) * 64;
  const int lrow = tid >> 2, lcol = (tid & 3) * 8;
  const int fr = lane & 15, fq = (lane >> 4) * 8;
  f32x4 acc[4][4];
#pragma unroll
  for (int i = 0; i < 4; ++i)
#pragma unroll
    for (int j = 0; j < 4; ++j) acc[i][j] = (f32x4){0.f, 0.f, 0.f, 0.f};

  for (int k0 = 0; k0 < K; k0 += 32) {
    uint4 a0 = *(const uint4*)(A + (size_t)(m0 + lrow) * lda + k0 + lcol);
    uint4 a1 = *(const uint4*)(A + (size_t)(m0 + 64 + lrow) * lda + k0 + lcol);
    uint4 b0 = *(const uint4*)(W + (size_t)(n0 + lrow) * ldw + k0 + lcol);
    uint4 b1 = *(const uint4*)(W + (size_t)(n0 + 64 + lrow) * ldw + k0 + lcol);
    *(uint4*)(&la[lrow][lcol]) = a0;
    *(uint4*)(&la[64 + lrow][lcol]) = a1;
    *(uint4*)(&lb[lrow][lcol]) = b0;
    *(uint4*)(&lb[64 + lrow][lcol]) = b1;
    __syncthreads();
    short8 af[4], bf[4];
#pragma unroll
    for (int i = 0; i < 4; ++i) af[i] = *(const short8*)(&la[wm + i * 16 + fr][fq]);
#pragma unroll
    for (int j = 0; j < 4; ++j) bf[j] = *(const short8*)(&lb[wn + j * 16 + fr][fq]);
#pragma unroll
    for (int i = 0; i < 4; ++i)
#pragma unroll
      for (int j = 0; j < 4; ++j)
        acc[i][j] = __builtin_amdgcn_mfma_f32_16x16x32_bf16(af[i], bf[j], acc[i][j], 0, 0, 0);
    __syncthreads();
  }
  const int rq = (lane >> 4) * 4;
#pragma unroll
  for (int i = 0; i < 4; ++i)
#pragma unroll
    for (int j = 0; j < 4; ++j) {
      int n = n0 + wn + j * 16 + fr;
      float bv = bias ? bias[n] : 0.f;
#pragma unroll
      for (int r2 = 0; r2 < 4; ++r2) {
        int m = m0 + wm + i * 16 + rq + r2;
        C[(size_t)m * ldc + n] = acc[i][j][r2] + bv;
      }
    }
}

// ---------------------------------------------------------------------------
// 2b. Merged QU+RT+PD GEMM launch. ldc=1280, K=512 for all three.
// blocks [0,640): QU = srepbf[8192,512] @ wpack2^T
// blocks [640,680): RT = topbf[512,512] @ wpack1^T
// blocks [680,690): PD = dvbf[32,512] @ wpack1^T (M-clamped loads)
__global__ __launch_bounds__(256) void gemm3_kernel(
    const __hip_bfloat16* __restrict__ srepbf, const __hip_bfloat16* __restrict__ topbf,
    const __hip_bfloat16* __restrict__ dvbf,
    const __hip_bfloat16* __restrict__ wpack1, const __hip_bfloat16* __restrict__ wpack2,
    float* __restrict__ QU, float* __restrict__ RT, float* __restrict__ PD) {
  const int blk = blockIdx.x;
  const __hip_bfloat16* A; const __hip_bfloat16* W; float* C;
  int M, m0, n0;
  if (blk < 640) {
    A = srepbf; W = wpack2; C = QU; M = 8192;
    m0 = (blk & 63) * 128; n0 = (blk >> 6) * 128;
  } else if (blk < 680) {
    int x = blk - 640;
    A = topbf; W = wpack1; C = RT; M = 512;
    m0 = (x & 3) * 128; n0 = (x >> 2) * 128;
  } else {
    int x = blk - 680;
    A = dvbf; W = wpack1; C = PD; M = 32;
    m0 = 0; n0 = x * 128;
  }
  __shared__ unsigned short la[128][40];
  __shared__ unsigned short lb[128][40];
  const int tid = threadIdx.x;
  const int lane = tid & 63, wid = tid >> 6;
  const int wm = (wid >> 1) * 64, wn = (wid & 1) * 64;
  const int lrow = tid >> 2, lcol = (tid & 3) * 8;
  const int fr = lane & 15, fq = (lane >> 4) * 8;
  int ar0 = m0 + lrow;      if (ar0 > M - 1) ar0 = M - 1;
  int ar1 = m0 + 64 + lrow; if (ar1 > M - 1) ar1 = M - 1;
  f32x4 acc[4][4];
#pragma unroll
  for (int i = 0; i < 4; ++i)
#pragma unroll
    for (int j = 0; j < 4; ++j) acc[i][j] = (f32x4){0.f, 0.f, 0.f, 0.f};

  for (int k0 = 0; k0 < 512; k0 += 32) {
    uint4 a0 = *(const uint4*)(A + (size_t)ar0 * 512 + k0 + lcol);
    uint4 a1 = *(const uint4*)(A + (size_t)ar1 * 512 + k0 + lcol);
    uint4 b0 = *(const uint4*)(W + (size_t)(n0 + lrow) * 512 + k0 + lcol);
    uint4 b1 = *(const uint4*)(W + (size_t)(n0 + 64 + lrow) * 512 + k0 + lcol);
    *(uint4*)(&la[lrow][lcol]) = a0;
    *(uint4*)(&la[64 + lrow][lcol]) = a1;
    *(uint4*)(&lb[lrow][lcol]) = b0;
    *(uint4*)(&lb[64 + lrow][lcol]) = b1;
    __syncthreads();
    short8 af[4], bf[4];
#pragma unroll
    for (int i = 0; i < 4; ++i) af[i] = *(const short8*)(&la[wm + i * 16 + fr][fq]);
#pragma unroll
    for (int j = 0; j < 4; ++j) bf[j] = *(const short8*)(&lb[wn + j * 16 + fr][fq]);
#pragma unroll
    for (int i = 0; i < 4; ++i)
#pragma unroll
      for (int j = 0; j < 4; ++j)
        acc[i][j] = __builtin_amdgcn_mfma_f32_16x16x32_bf16(af[i], bf[j], acc[i][j], 0, 0, 0);
    __syncthreads();
  }
  const int rq = (lane >> 4) * 4;
#pragma unroll
  for (int i = 0; i < 4; ++i)
#pragma unroll
    for (int j = 0; j < 4; ++j) {
      int n = n0 + wn + j * 16 + fr;
#pragma unroll
      for (int r2 = 0; r2 < 4; ++r2) {
        int m = m0 + wm + i * 16 + rq + r2;
        if (m < M) C[(size_t)m * 1280 + n] = acc[i][j][r2];
      }
    }
}

// ---------------------------------------------------------------------------
// 4. Persistent-weight MFMA GRU (v4 structure — best measured: 329 us).
// Five schedule variants (v1-v5) all landed at ~3100 cy/step with 8 waves;
// per-step MFMA issue time is invariant (~1530 cy = 384 MFMAs x 4 cy), and
// 4-wave blocks regressed. PARKED: do not touch without an algorithmic change.
// gi is now the fused [8192][1536] array: fwd = cols 0..767, bwd = 768..1535.
//
// Blocks [0,64): GRU recurrence (dir=blk>>5, b=blk&31), block 512.
// Blocks [64,384): build Wpack1/Wpack2 bf16 [1280][512] while the GRU runs.
__global__ __launch_bounds__(512, 1) void gru_mfma_kernel(
    const float* __restrict__ gi_cat,
    const __hip_bfloat16* __restrict__ whhbf_f, const __hip_bfloat16* __restrict__ whhbf_b,
    const float* __restrict__ bhh_f, const float* __restrict__ bhh_b,
    float* __restrict__ sent_rep, __hip_bfloat16* __restrict__ sent_rep_bf,
    float* __restrict__ hT_f, float* __restrict__ hT_b,
    const float* __restrict__ w_att, const float* __restrict__ w_dna,
    __hip_bfloat16* __restrict__ wpack1, __hip_bfloat16* __restrict__ wpack2) {
  __shared__ float gi_lds[2][8][768];          // 49152 B (lane-linear for global_load_lds)
  __shared__ __hip_bfloat16 h_bf[2][256];      // 1024 B double-buffered h
  __shared__ float gh[768];                    // 3072 B matvec handoff
  __shared__ float stg32[2][8][256];           // 16384 B double-buffered store staging
  const int blk = blockIdx.x;
  const int tid = threadIdx.x;

  if (blk >= 64) {
    // ---- fused weight-pack branch (no barriers, no LDS) ----
    const size_t q = (size_t)(blk - 64) * 512 + tid;
    size_t flat = q * 8;                        // [0, 1310720)
    const size_t HALF = (size_t)1280 * 512;     // 655360
    const bool second = flat >= HALF;
    size_t r = second ? flat - HALF : flat;
    int n = (int)(r >> 9), k0 = (int)(r & 511);
    __hip_bfloat16* dst = second ? wpack2 : wpack1;
#pragma unroll
    for (int j = 0; j < 8; ++j) {
      int k = k0 + j;
      float v;
      if (!second)
        v = (n < 1024) ? w_att[(size_t)k * 1024 + n]
                       : w_dna[(size_t)(512 + k) * 256 + (n - 1024)];
      else
        v = (n < 1024) ? w_att[(size_t)(512 + k) * 1024 + n]
                       : w_dna[(size_t)k * 256 + (n - 1024)];
      dst[(size_t)n * 512 + k] = __float2bfloat16(v);
    }
    return;
  }

  // ---- GRU recurrence branch ----
  const int dir = blk >> 5, b = blk & 31;
  const int lane = tid & 63, w = tid >> 6;
  const float* gi = gi_cat + (dir ? 768 : 0);   // row stride 1536
  const __hip_bfloat16* whh = dir ? whhbf_b : whhbf_f;
  const float* bhh = dir ? bhh_b : bhh_f;

  // prologue: DMA tile 0 into buf 0 (512 threads x 3 x 16B)
  {
#pragma unroll
    for (int i = 0; i < 3; ++i) {
      int idx = tid + i * 512;               // 0..1535 = 8 rows x 192 float4
      int u = idx / 192;
      int c4 = (idx - u * 192) * 4;
      int s = dir ? (255 - u) : u;
      const float* g = gi + (size_t)((b << 8) + s) * 1536 + c4;
      __builtin_amdgcn_global_load_lds(
          (const __attribute__((address_space(1))) unsigned int*)g,
          (__attribute__((address_space(3))) unsigned int*)&gi_lds[0][u][c4], 16, 0, 0);
    }
  }
  if (tid < 256) h_bf[0][tid] = __float2bfloat16(0.f);

  // weight fragments: wave w covers outputs [96w, 96w+96), 6 n-tiles of 16
  const int fr = lane & 15, kq = (lane >> 4) * 8;
  short8 bfrag[6][8];
  {
    const int n0 = w * 96 + fr;
#pragma unroll
    for (int nt = 0; nt < 6; ++nt)
#pragma unroll
      for (int kt = 0; kt < 8; ++kt)
        bfrag[nt][kt] = *(const short8*)(whh + (size_t)(n0 + nt * 16) * 256 + kt * 32 + kq);
  }

  float bhr = 0.f, bhz = 0.f, bhn = 0.f, hprev = 0.f;
  if (tid < 256) { bhr = bhh[tid]; bhz = bhh[256 + tid]; bhn = bhh[512 + tid]; }

  // prologue: wait DMA + h init, then converge
  asm volatile("s_waitcnt vmcnt(0) lgkmcnt(0)\n\ts_barrier" ::: "memory");

  for (int t = 0; t < Sd; ++t) {
    const int rb = t & 1, wb = rb ^ 1;

    // preload this step's gi values (buffer stable since prev barrier B;
    // DMA landing for the group was guaranteed at t%8==7 of the prev step)
    float gl0 = 0.f, gl1 = 0.f, gl2 = 0.f;
    if (tid < 256) {
      const float* gl = gi_lds[(t >> 3) & 1][t & 7];
      gl0 = gl[tid]; gl1 = gl[256 + tid]; gl2 = gl[512 + tid];
    }

    // --- MFMA phase (all 8 waves, 48 MFMAs each) ---
    f32x4 acc[6];
#pragma unroll
    for (int nt = 0; nt < 6; ++nt) acc[nt] = (f32x4){0.f, 0.f, 0.f, 0.f};
#pragma unroll
    for (int kt = 0; kt < 8; ++kt) {
      // broadcast h chunk; A rows 0-15 all replicate h (only D row 0 is read)
      short8 av = *(const short8*)(&h_bf[rb][kt * 32 + kq]);
#pragma unroll
      for (int nt = 0; nt < 6; ++nt)
        acc[nt] = __builtin_amdgcn_mfma_f32_16x16x32_bf16(av, bfrag[nt][kt], acc[nt], 0, 0, 0);
      __builtin_amdgcn_sched_group_barrier(0x100, 1, 0);  // DS_READ x1
      __builtin_amdgcn_sched_group_barrier(0x008, 6, 0);  // MFMA x6
    }
    if (lane < 16) {
#pragma unroll
      for (int nt = 0; nt < 6; ++nt) gh[w * 96 + nt * 16 + lane] = acc[nt][0];
    }
    asm volatile("s_waitcnt lgkmcnt(0)\n\ts_barrier" ::: "memory");   // barrier A: gh visible

    if (tid < 256) {
      // --- elementwise waves 0-3: one h value per lane ---
      float rr = fsigm(gl0 + gh[tid] + bhr);
      float zz = fsigm(gl1 + gh[256 + tid] + bhz);
      float nn = ftanh(gl2 + rr * (gh[512 + tid] + bhn));
      float hn = (1.f - zz) * nn + zz * hprev;
      hprev = hn;
      h_bf[wb][tid] = __float2bfloat16(hn);
      stg32[(t >> 3) & 1][t & 7][tid] = hn;
    } else if ((t & 7) == 0) {
      // --- memory waves 4-7: overlapped with elementwise ---
      if (t + 8 < Sd) {
        // prefetch tile t+8 into the buffer NOT read this group
        const int buf = ((t >> 3) + 1) & 1;
#pragma unroll
        for (int i = 0; i < 6; ++i) {
          int idx = (tid - 256) + i * 256;   // 0..1535
          int u = idx / 192;
          int c4 = (idx - u * 192) * 4;
          int s = dir ? (255 - (t + 8 + u)) : (t + 8 + u);
          const float* g = gi + (size_t)((b << 8) + s) * 1536 + c4;
          __builtin_amdgcn_global_load_lds(
              (const __attribute__((address_space(1))) unsigned int*)g,
              (__attribute__((address_space(3))) unsigned int*)&gi_lds[buf][u][c4], 16, 0, 0);
        }
      }
      if (t >= 8) {
        // store the group finished last step (steps t-8..t-1)
        const int base = t - 8;
        const int gp = ((t >> 3) - 1) & 1;
        const int d = tid - 256;
#pragma unroll
        for (int u = 0; u < 8; ++u) {
          int sg = dir ? (255 - (base + u)) : (base + u);
          size_t rowg = (size_t)((b << 8) + sg);
          int col = dir ? (256 + d) : d;
          float v = stg32[gp][u][d];
          sent_rep[rowg * 512 + col] = v;
          sent_rep_bf[rowg * 512 + col] = __float2bfloat16(v);
        }
      }
    }
    // memory waves: guarantee the NEXT group's tile (DMA'd at t-7) has landed
    // before barrier B of the group's last step -> step-top preload is safe.
    if (w >= 4 && (t & 7) == 7)
      asm volatile("s_waitcnt vmcnt(0)" ::: "memory");
    asm volatile("s_waitcnt lgkmcnt(0)\n\ts_barrier" ::: "memory");   // barrier B: h visible
  }

  // epilogue: store last group (31, in stg32[1]) + final hidden
  if (w >= 4) {
    const int base = 248, d = tid - 256;
#pragma unroll
    for (int u = 0; u < 8; ++u) {
      int sg = dir ? (255 - (base + u)) : (base + u);
      size_t rowg = (size_t)((b << 8) + sg);
      int col = dir ? (256 + d) : d;
      float v = stg32[1][u][d];
      sent_rep[rowg * 512 + col] = v;
      sent_rep_bf[rowg * 512 + col] = __float2bfloat16(v);
    }
  } else {
    (dir ? hT_b : hT_f)[b * 256 + tid] = hprev;
  }
}

// ---------------------------------------------------------------------------
// 5. FUSED topic_mat + doc_vec. block 256.
// blocks [0,512): topic boundary differencing (bt = blk)
// blocks [512,544): doc_vec torch view(B,2H) (b = blk-512, 2 elems/thread)
__global__ void dt_kernel(const int* __restrict__ tse, const float* __restrict__ sent_rep,
                          const float* __restrict__ hTf, const float* __restrict__ hTb,
                          __hip_bfloat16* __restrict__ topic_bf, __hip_bfloat16* __restrict__ dv) {
  const int blk = blockIdx.x;
  const int tid = threadIdx.x;
  if (blk < 512) {
    int bt = blk;
    int b = bt >> 4;
    int st = tse[bt * 2], en = tse[bt * 2 + 1];   // 1-indexed
    auto pad = [&](int i, int col) -> float {
      if (i < 1 || i > Sd) return 0.f;
      return sent_rep[((size_t)((b << 8) + (i - 1))) * 512 + col];
    };
    float fwd = pad(en, tid) - pad(st - 1, tid);
    float bwd = pad(st, Hd + tid) - pad(en + 1, Hd + tid);
    topic_bf[(size_t)bt * 512 + tid] = __float2bfloat16(fwd);
    topic_bf[(size_t)bt * 512 + Hd + tid] = __float2bfloat16(bwd);
    return;
  }
  const int b = blk - 512;
#pragma unroll
  for (int r = 0; r < 2; ++r) {
    int jj = tid + r * 256;
    int idx = b * 512 + jj;
    int dsel = idx >> 13;            // /8192
    int rem = idx & 8191;
    int bp = rem >> 8, hp = rem & 255;
    float v = (dsel ? hTb : hTf)[bp * Hd + hp];
    dv[idx] = __float2bfloat16(v);
  }
}

// ---------------------------------------------------------------------------
// 7. attention scores. grid 8192 (b*256+s), block 256.
__global__ void scores_kernel(const float* __restrict__ PD, const float* __restrict__ RT,
                              const float* __restrict__ QU, const float* __restrict__ v_att,
                              const int* __restrict__ tse,
                              float* __restrict__ dsc, float* __restrict__ tsc) {
  int r = blockIdx.x;
  int b = r >> 8, s = r & 255;
  int tid = threadIdx.x;
  int tsel = Td - 1;
  for (int t = 0; t < Td; ++t) {
    if (tse[(b * Td + t) * 2 + 1] >= s + 1) { tsel = t; break; }
  }
  const float* q = QU + (size_t)r * 1280;
  const float* p = PD + (size_t)b * 1280;
  const float* rr = RT + (size_t)(b * Td + tsel) * 1280;
  float accd = 0.f, acct = 0.f;
  for (int n = tid; n < 1024; n += 256) {
    float qv = q[n];
    float vv = v_att[n];
    accd += ftanh(p[n] + qv) * vv;
    acct += ftanh(rr[n] + qv) * vv;
  }
  __shared__ float s1[256], s2[256];
  s1[tid] = accd; s2[tid] = acct;
  __syncthreads();
  for (int off = 128; off > 0; off >>= 1) {
    if (tid < off) { s1[tid] += s1[tid + off]; s2[tid] += s2[tid + off]; }
    __syncthreads();
  }
  if (tid == 0) { dsc[r] = s1[0]; tsc[r] = s2[0]; }
}

// 8. softmax over s per batch (both score sets). grid 32, block 256.
__global__ void softmax_kernel(const float* __restrict__ dsc, const float* __restrict__ tsc,
                               float* __restrict__ dw, float* __restrict__ tw) {
  int b = blockIdx.x, s = threadIdx.x;
  __shared__ float red[256];
  for (int which = 0; which < 2; ++which) {
    const float* src = which ? tsc : dsc;
    float v = src[b * Sd + s];
    red[s] = v; __syncthreads();
    for (int off = 128; off > 0; off >>= 1) {
      if (s < off) red[s] = fmaxf(red[s], red[s + off]);
      __syncthreads();
    }
    float m = red[0]; __syncthreads();
    float e = __expf(v - m);
    red[s] = e; __syncthreads();
    for (int off = 128; off > 0; off >>= 1) {
      if (s < off) red[s] += red[s + off];
      __syncthreads();
    }
    float sum = red[0]; __syncthreads();
    (which ? tw : dw)[b * Sd + s] = e / sum;
  }
}

// 9. final head. grid 8192, block 256. OUTPUT IS FP32.
__global__ void final_kernel(const float* __restrict__ QU, const float* __restrict__ PD,
                             const float* __restrict__ RT, const float* __restrict__ dw,
                             const float* __restrict__ tw, const float* __restrict__ b_dna,
                             const float* __restrict__ w_out,
                             const float* __restrict__ b_out,
                             const int* __restrict__ tse, float* __restrict__ out) {
  int r = blockIdx.x;
  int b = r >> 8, s = r & 255;
  int dd = threadIdx.x;
  int tsel = Td - 1;
  for (int t = 0; t < Td; ++t) {
    if (tse[(b * Td + t) * 2 + 1] >= s + 1) { tsel = t; break; }
  }
  float wdv = dw[b * Sd + s], wtv = tw[b * Sd + s];
  float x = QU[(size_t)r * 1280 + 1024 + dd] + wdv * PD[(size_t)b * 1280 + 1024 + dd] +
            wtv * RT[(size_t)(b * Td + tsel) * 1280 + 1024 + dd] + b_dna[dd];
  x = fmaxf(x, 0.f);
  float term = x * w_out[dd];
  __shared__ float red[256];
  red[dd] = term; __syncthreads();
  for (int off = 128; off > 0; off >>= 1) {
    if (dd < off) red[dd] += red[dd + off];
    __syncthreads();
  }
  if (dd == 0) out[r] = red[0] + b_out[0];
}

// ---------------------------------------------------------------------------
extern "C" void kernel_launch(void* const* d_in, const int* in_sizes, int n_in,
                              void* d_out, int out_size, void* d_ws, size_t ws_size,
                              hipStream_t stream) {
  const int* word_ids = (const int*)d_in[0];
  const int* tse      = (const int*)d_in[1];
  const float* emb   = (const float*)d_in[2];
  const float* wih_f = (const float*)d_in[3];
  const float* whh_f = (const float*)d_in[4];
  const float* bih_f = (const float*)d_in[5];
  const float* bhh_f = (const float*)d_in[6];
  const float* wih_b = (const float*)d_in[7];
  const float* whh_b = (const float*)d_in[8];
  const float* bih_b = (const float*)d_in[9];
  const float* bhh_b = (const float*)d_in[10];
  const float* w_att = (const float*)d_in[11];
  const float* v_att = (const float*)d_in[12];
  const float* w_dna = (const float*)d_in[13];
  const float* b_dna = (const float*)d_in[14];
  const float* w_out = (const float*)d_in[15];
  const float* b_out = (const float*)d_in[16];
  float* out = (float*)d_out;
  char* ws = (char*)d_ws;

  const int M = Bd * Sd;  // 8192

  // workspace layout (bytes)
  size_t off = 0;
  auto alloc = [&](size_t sz) { size_t o = off; off += (sz + 255) & ~(size_t)255; return o; };
  size_t o_svbf   = alloc((size_t)M * EP * 2);          // A_pad bf16 [8192,320]
  size_t o_wpad   = alloc((size_t)2 * 768 * EP * 2);    // wih pad f+b, ADJACENT
  size_t o_whhbf  = alloc((size_t)768 * Hd * 2 * 2);    // whh f+b bf16
  size_t o_wpack1 = alloc((size_t)1280 * 512 * 2);      // [W_att[:512];W_dna[512:]] ^T bf16
  size_t o_wpack2 = alloc((size_t)1280 * 512 * 2);      // [W_att[512:];W_dna[:512]] ^T bf16
  size_t o_bcat   = alloc((size_t)1536 * 4);            // bih_f|bih_b fp32
  size_t o_hTf    = alloc((size_t)Bd * Hd * 4);
  size_t o_hTb    = alloc((size_t)Bd * Hd * 4);
  size_t o_dvbf   = alloc((size_t)Bd * 512 * 2);        // doc_vec bf16
  size_t o_topbf  = alloc((size_t)Bd * Td * 512 * 2);   // topic_mat bf16
  size_t o_PD     = alloc((size_t)Bd * 1280 * 4);       // [P | dvd]
  size_t o_RT     = alloc((size_t)Bd * Td * 1280 * 4);  // [R | tvd]
  size_t o_dsc    = alloc((size_t)Bd * Sd * 4);
  size_t o_tsc    = alloc((size_t)Bd * Sd * 4);
  size_t o_dw     = alloc((size_t)Bd * Sd * 4);
  size_t o_tw     = alloc((size_t)Bd * Sd * 4);
  size_t o_srep32 = alloc((size_t)M * 512 * 4);         // sent_rep fp32
  size_t o_srepbf = alloc((size_t)M * 512 * 2);         // sent_rep bf16
  size_t o_gicat  = alloc((size_t)M * 1536 * 4);        // fused gi [8192,1536] fp32
  // QU [8192,1280] f32 overlays the dead gi region after the GRU
  size_t o_QU = o_gicat;
  (void)ws_size;

  __hip_bfloat16* svbf   = (__hip_bfloat16*)(ws + o_svbf);
  __hip_bfloat16* wpadf  = (__hip_bfloat16*)(ws + o_wpad);
  __hip_bfloat16* wpadb  = wpadf + 768 * EP;
  __hip_bfloat16* whhbf_f = (__hip_bfloat16*)(ws + o_whhbf);
  __hip_bfloat16* whhbf_b = whhbf_f + 768 * Hd;
  __hip_bfloat16* wpack1 = (__hip_bfloat16*)(ws + o_wpack1);
  __hip_bfloat16* wpack2 = (__hip_bfloat16*)(ws + o_wpack2);
  float* bcat = (float*)(ws + o_bcat);
  float* hTf = (float*)(ws + o_hTf);
  float* hTb = (float*)(ws + o_hTb);
  __hip_bfloat16* dvbf  = (__hip_bfloat16*)(ws + o_dvbf);
  __hip_bfloat16* topbf = (__hip_bfloat16*)(ws + o_topbf);
  float* PD  = (float*)(ws + o_PD);
  float* RT  = (float*)(ws + o_RT);
  float* dsc = (float*)(ws + o_dsc);
  float* tsc = (float*)(ws + o_tsc);
  float* dw  = (float*)(ws + o_dw);
  float* tw  = (float*)(ws + o_tw);
  float* srep32 = (float*)(ws + o_srep32);
  __hip_bfloat16* srepbf = (__hip_bfloat16*)(ws + o_srepbf);
  float* gicat = (float*)(ws + o_gicat);
  float* QU  = (float*)(ws + o_QU);

  // 1. fused: sentence means + weight prep + bias concat
  sentprep_kernel<<<10962, 320, 0, stream>>>(word_ids, emb, svbf,
                                             wih_f, wih_b, whh_f, whh_b,
                                             wpadf, wpadb, whhbf_f, whhbf_b,
                                             bih_f, bih_b, bcat);
  // 2. fused input projection: gi_cat = svbf @ [Wih_f;Wih_b]^T + bcat (N=1536)
  {
    dim3 grid(M / 128, 1536 / 128);
    gemm128_xwt_kernel<<<grid, 256, 0, stream>>>(svbf, EP, wpadf, EP, gicat, 1536,
                                                 M, 1536, EP, bcat);
  }
  // 3. GRU recurrence + fused att/dna weight packing on idle CUs
  gru_mfma_kernel<<<384, 512, 0, stream>>>(gicat, whhbf_f, whhbf_b, bhh_f, bhh_b,
                                           srep32, srepbf, hTf, hTb,
                                           w_att, w_dna, wpack1, wpack2);
  // 4. fused topic_mat + doc_vec
  dt_kernel<<<544, 256, 0, stream>>>(tse, srep32, hTf, hTb, topbf, dvbf);
  // 5. merged QU+RT+PD GEMMs (one launch, 690 blocks)
  gemm3_kernel<<<690, 256, 0, stream>>>(srepbf, topbf, dvbf, wpack1, wpack2, QU, RT, PD);
  // 6. scores + softmax
  scores_kernel<<<M, 256, 0, stream>>>(PD, RT, QU, v_att, tse, dsc, tsc);
  softmax_kernel<<<Bd, 256, 0, stream>>>(dsc, tsc, dw, tw);
  // 7. fused dense head -> logits (fp32)
  final_kernel<<<M, 256, 0, stream>>>(QU, PD, RT, dw, tw, b_dna, w_out, b_out, tse, out);
}

// Round 8
// 536.732 us; speedup vs baseline: 1.1087x; 1.1087x over previous
//
#include <hip/hip_runtime.h>
#include <hip/hip_bf16.h>
#include <math.h>

// Dims (fixed by the problem)
#define Bd 32
#define Sd 256
#define Ld 24
#define Ed 300
#define Hd 256
#define Td 16
#define Dd 256
#define EP 320    // E padded to multiple of 32

using short8 = __attribute__((ext_vector_type(8))) short;
using f32x4  = __attribute__((ext_vector_type(4))) float;

// fast transcendentals (v_exp_f32 path; saturate correctly at +-inf)
__device__ __forceinline__ float fsigm(float x) { return 1.f / (1.f + __expf(-x)); }
__device__ __forceinline__ float ftanh(float x) {
  float e = __expf(2.f * x);
  return 1.f - 2.f / (e + 1.f);
}

// ---------------------------------------------------------------------------
// 1. FUSED sentence means + GRU-weight prep + bias concat. block 320.
// blocks [0,8192): A_pad[r][k] = bf16(mean_w emb[word_ids[r][w]][k])
// blocks [8192,10962): prep (wih pad f+b, whh f2bf f+b, bias_cat[1536])
__global__ void sentprep_kernel(const int* __restrict__ wids,
                                const float* __restrict__ emb,
                                __hip_bfloat16* __restrict__ apad,
                                const float* __restrict__ wih_f, const float* __restrict__ wih_b,
                                const float* __restrict__ whh_f, const float* __restrict__ whh_b,
                                __hip_bfloat16* __restrict__ wpadf, __hip_bfloat16* __restrict__ wpadb,
                                __hip_bfloat16* __restrict__ whhbf_f, __hip_bfloat16* __restrict__ whhbf_b,
                                const float* __restrict__ bih_f, const float* __restrict__ bih_b,
                                float* __restrict__ bias_cat) {
  const int blk = blockIdx.x;
  const int tid = threadIdx.x;
  if (blk < 8192) {
    __shared__ int ids[Ld];
    if (tid < Ld) ids[tid] = wids[blk * Ld + tid];
    __syncthreads();
    float acc = 0.f;
    if (tid < Ed) {
#pragma unroll
      for (int w = 0; w < Ld; ++w) acc += emb[(size_t)ids[w] * Ed + tid];
      acc *= (1.f / 24.f);
    }
    apad[blk * EP + tid] = __float2bfloat16(tid < Ed ? acc : 0.f);
    return;
  }
  const int i = (blk - 8192) * 320 + tid;
  const int PW = 768 * EP;     // 245760
  const int WH = 768 * Hd;     // 196608
  if (i < 2 * PW) {
    const float* src = (i < PW) ? wih_f : wih_b;
    __hip_bfloat16* dst = (i < PW) ? wpadf : wpadb;
    int j = (i < PW) ? i : i - PW;
    int n = j / EP, k = j % EP;
    dst[j] = __float2bfloat16(k < Ed ? src[n * Ed + k] : 0.f);
  } else if (i < 2 * PW + 2 * WH) {
    int j = i - 2 * PW;
    const float* src = (j < WH) ? whh_f : whh_b;
    __hip_bfloat16* dst = (j < WH) ? whhbf_f : whhbf_b;
    int k = (j < WH) ? j : j - WH;
    dst[k] = __float2bfloat16(src[k]);
  } else if (i < 2 * PW + 2 * WH + 1536) {
    int j = i - 2 * PW - 2 * WH;
    bias_cat[j] = (j < 768) ? bih_f[j] : bih_b[j - 768];
  }
}

// ---------------------------------------------------------------------------
// 2. gi GEMM: one launch, N=1536 over [Wih_f;Wih_b], SPLIT epilogue writes:
// n<768 -> gif[m*768+n], else gib[m*768+(n-768)]. Keeps the GRU's proven
// contiguous-per-direction gi layout (stride-1536 layout cost +54us in v7).
// 128-tile, 4 waves, LDS rows padded to 40 shorts (bank-friendly).
__global__ __launch_bounds__(256) void gemm_gi_kernel(
    const __hip_bfloat16* __restrict__ A,      // svbf [8192,320]
    const __hip_bfloat16* __restrict__ W,      // wpadf|wpadb adjacent [1536,320]
    float* __restrict__ gif, float* __restrict__ gib,
    const float* __restrict__ bias_cat) {
  __shared__ unsigned short la[128][40];
  __shared__ unsigned short lb[128][40];
  const int tid = threadIdx.x;
  const int m0 = blockIdx.x * 128, n0 = blockIdx.y * 128;
  const int lane = tid & 63, wid = tid >> 6;
  const int wm = (wid >> 1) * 64, wn = (wid & 1) * 64;
  const int lrow = tid >> 2, lcol = (tid & 3) * 8;
  const int fr = lane & 15, fq = (lane >> 4) * 8;
  f32x4 acc[4][4];
#pragma unroll
  for (int i = 0; i < 4; ++i)
#pragma unroll
    for (int j = 0; j < 4; ++j) acc[i][j] = (f32x4){0.f, 0.f, 0.f, 0.f};

  for (int k0 = 0; k0 < EP; k0 += 32) {
    uint4 a0 = *(const uint4*)(A + (size_t)(m0 + lrow) * EP + k0 + lcol);
    uint4 a1 = *(const uint4*)(A + (size_t)(m0 + 64 + lrow) * EP + k0 + lcol);
    uint4 b0 = *(const uint4*)(W + (size_t)(n0 + lrow) * EP + k0 + lcol);
    uint4 b1 = *(const uint4*)(W + (size_t)(n0 + 64 + lrow) * EP + k0 + lcol);
    *(uint4*)(&la[lrow][lcol]) = a0;
    *(uint4*)(&la[64 + lrow][lcol]) = a1;
    *(uint4*)(&lb[lrow][lcol]) = b0;
    *(uint4*)(&lb[64 + lrow][lcol]) = b1;
    __syncthreads();
    short8 af[4], bf[4];
#pragma unroll
    for (int i = 0; i < 4; ++i) af[i] = *(const short8*)(&la[wm + i * 16 + fr][fq]);
#pragma unroll
    for (int j = 0; j < 4; ++j) bf[j] = *(const short8*)(&lb[wn + j * 16 + fr][fq]);
#pragma unroll
    for (int i = 0; i < 4; ++i)
#pragma unroll
      for (int j = 0; j < 4; ++j)
        acc[i][j] = __builtin_amdgcn_mfma_f32_16x16x32_bf16(af[i], bf[j], acc[i][j], 0, 0, 0);
    __syncthreads();
  }
  const int rq = (lane >> 4) * 4;
#pragma unroll
  for (int i = 0; i < 4; ++i)
#pragma unroll
    for (int j = 0; j < 4; ++j) {
      int n = n0 + wn + j * 16 + fr;
      float bv = bias_cat[n];
      float* Cp = (n < 768) ? gif : gib;
      int nn = (n < 768) ? n : n - 768;
#pragma unroll
      for (int r2 = 0; r2 < 4; ++r2) {
        int m = m0 + wm + i * 16 + rq + r2;
        Cp[(size_t)m * 768 + nn] = acc[i][j][r2] + bv;
      }
    }
}

// ---------------------------------------------------------------------------
// 2b. Merged QU+RT+PD GEMM launch. ldc=1280, K=512 for all three.
// blocks [0,640): QU = srepbf[8192,512] @ wpack2^T
// blocks [640,680): RT = topbf[512,512] @ wpack1^T
// blocks [680,690): PD = dvbf[32,512] @ wpack1^T (M-clamped loads)
__global__ __launch_bounds__(256) void gemm3_kernel(
    const __hip_bfloat16* __restrict__ srepbf, const __hip_bfloat16* __restrict__ topbf,
    const __hip_bfloat16* __restrict__ dvbf,
    const __hip_bfloat16* __restrict__ wpack1, const __hip_bfloat16* __restrict__ wpack2,
    float* __restrict__ QU, float* __restrict__ RT, float* __restrict__ PD) {
  const int blk = blockIdx.x;
  const __hip_bfloat16* A; const __hip_bfloat16* W; float* C;
  int M, m0, n0;
  if (blk < 640) {
    A = srepbf; W = wpack2; C = QU; M = 8192;
    m0 = (blk & 63) * 128; n0 = (blk >> 6) * 128;
  } else if (blk < 680) {
    int x = blk - 640;
    A = topbf; W = wpack1; C = RT; M = 512;
    m0 = (x & 3) * 128; n0 = (x >> 2) * 128;
  } else {
    int x = blk - 680;
    A = dvbf; W = wpack1; C = PD; M = 32;
    m0 = 0; n0 = x * 128;
  }
  __shared__ unsigned short la[128][40];
  __shared__ unsigned short lb[128][40];
  const int tid = threadIdx.x;
  const int lane = tid & 63, wid = tid >> 6;
  const int wm = (wid >> 1) * 64, wn = (wid & 1) * 64;
  const int lrow = tid >> 2, lcol = (tid & 3) * 8;
  const int fr = lane & 15, fq = (lane >> 4) * 8;
  int ar0 = m0 + lrow;      if (ar0 > M - 1) ar0 = M - 1;
  int ar1 = m0 + 64 + lrow; if (ar1 > M - 1) ar1 = M - 1;
  f32x4 acc[4][4];
#pragma unroll
  for (int i = 0; i < 4; ++i)
#pragma unroll
    for (int j = 0; j < 4; ++j) acc[i][j] = (f32x4){0.f, 0.f, 0.f, 0.f};

  for (int k0 = 0; k0 < 512; k0 += 32) {
    uint4 a0 = *(const uint4*)(A + (size_t)ar0 * 512 + k0 + lcol);
    uint4 a1 = *(const uint4*)(A + (size_t)ar1 * 512 + k0 + lcol);
    uint4 b0 = *(const uint4*)(W + (size_t)(n0 + lrow) * 512 + k0 + lcol);
    uint4 b1 = *(const uint4*)(W + (size_t)(n0 + 64 + lrow) * 512 + k0 + lcol);
    *(uint4*)(&la[lrow][lcol]) = a0;
    *(uint4*)(&la[64 + lrow][lcol]) = a1;
    *(uint4*)(&lb[lrow][lcol]) = b0;
    *(uint4*)(&lb[64 + lrow][lcol]) = b1;
    __syncthreads();
    short8 af[4], bf[4];
#pragma unroll
    for (int i = 0; i < 4; ++i) af[i] = *(const short8*)(&la[wm + i * 16 + fr][fq]);
#pragma unroll
    for (int j = 0; j < 4; ++j) bf[j] = *(const short8*)(&lb[wn + j * 16 + fr][fq]);
#pragma unroll
    for (int i = 0; i < 4; ++i)
#pragma unroll
      for (int j = 0; j < 4; ++j)
        acc[i][j] = __builtin_amdgcn_mfma_f32_16x16x32_bf16(af[i], bf[j], acc[i][j], 0, 0, 0);
    __syncthreads();
  }
  const int rq = (lane >> 4) * 4;
#pragma unroll
  for (int i = 0; i < 4; ++i)
#pragma unroll
    for (int j = 0; j < 4; ++j) {
      int n = n0 + wn + j * 16 + fr;
#pragma unroll
      for (int r2 = 0; r2 < 4; ++r2) {
        int m = m0 + wm + i * 16 + rq + r2;
        if (m < M) C[(size_t)m * 1280 + n] = acc[i][j][r2];
      }
    }
}

// ---------------------------------------------------------------------------
// 4. Persistent-weight MFMA GRU (v4 structure — best measured: 329 us).
// Five schedule variants (v1-v5) all landed at ~3100 cy/step with 8 waves;
// per-step MFMA issue time is invariant (~1530 cy = 384 MFMAs x 4 cy), and
// 4-wave blocks regressed. gi MUST be contiguous per direction (stride 768):
// the fused stride-1536 layout cost +54us (v7). PARKED: do not touch.
//
// Blocks [0,64): GRU recurrence (dir=blk>>5, b=blk&31), block 512.
// Blocks [64,384): build Wpack1/Wpack2 bf16 [1280][512] while the GRU runs.
__global__ __launch_bounds__(512, 1) void gru_mfma_kernel(
    const float* __restrict__ gi_f, const float* __restrict__ gi_b,
    const __hip_bfloat16* __restrict__ whhbf_f, const __hip_bfloat16* __restrict__ whhbf_b,
    const float* __restrict__ bhh_f, const float* __restrict__ bhh_b,
    float* __restrict__ sent_rep, __hip_bfloat16* __restrict__ sent_rep_bf,
    float* __restrict__ hT_f, float* __restrict__ hT_b,
    const float* __restrict__ w_att, const float* __restrict__ w_dna,
    __hip_bfloat16* __restrict__ wpack1, __hip_bfloat16* __restrict__ wpack2) {
  __shared__ float gi_lds[2][8][768];          // 49152 B (lane-linear for global_load_lds)
  __shared__ __hip_bfloat16 h_bf[2][256];      // 1024 B double-buffered h
  __shared__ float gh[768];                    // 3072 B matvec handoff
  __shared__ float stg32[2][8][256];           // 16384 B double-buffered store staging
  const int blk = blockIdx.x;
  const int tid = threadIdx.x;

  if (blk >= 64) {
    // ---- fused weight-pack branch (no barriers, no LDS) ----
    const size_t q = (size_t)(blk - 64) * 512 + tid;
    size_t flat = q * 8;                        // [0, 1310720)
    const size_t HALF = (size_t)1280 * 512;     // 655360
    const bool second = flat >= HALF;
    size_t r = second ? flat - HALF : flat;
    int n = (int)(r >> 9), k0 = (int)(r & 511);
    __hip_bfloat16* dst = second ? wpack2 : wpack1;
#pragma unroll
    for (int j = 0; j < 8; ++j) {
      int k = k0 + j;
      float v;
      if (!second)
        v = (n < 1024) ? w_att[(size_t)k * 1024 + n]
                       : w_dna[(size_t)(512 + k) * 256 + (n - 1024)];
      else
        v = (n < 1024) ? w_att[(size_t)(512 + k) * 1024 + n]
                       : w_dna[(size_t)k * 256 + (n - 1024)];
      dst[(size_t)n * 512 + k] = __float2bfloat16(v);
    }
    return;
  }

  // ---- GRU recurrence branch ----
  const int dir = blk >> 5, b = blk & 31;
  const int lane = tid & 63, w = tid >> 6;
  const float* gi = dir ? gi_b : gi_f;
  const __hip_bfloat16* whh = dir ? whhbf_b : whhbf_f;
  const float* bhh = dir ? bhh_b : bhh_f;

  // prologue: DMA tile 0 into buf 0 (512 threads x 3 x 16B)
  {
#pragma unroll
    for (int i = 0; i < 3; ++i) {
      int idx = tid + i * 512;               // 0..1535 = 8 rows x 192 float4
      int u = idx / 192;
      int c4 = (idx - u * 192) * 4;
      int s = dir ? (255 - u) : u;
      const float* g = gi + (size_t)(((b << 8) + s) * 768 + c4);
      __builtin_amdgcn_global_load_lds(
          (const __attribute__((address_space(1))) unsigned int*)g,
          (__attribute__((address_space(3))) unsigned int*)&gi_lds[0][u][c4], 16, 0, 0);
    }
  }
  if (tid < 256) h_bf[0][tid] = __float2bfloat16(0.f);

  // weight fragments: wave w covers outputs [96w, 96w+96), 6 n-tiles of 16
  const int fr = lane & 15, kq = (lane >> 4) * 8;
  short8 bfrag[6][8];
  {
    const int n0 = w * 96 + fr;
#pragma unroll
    for (int nt = 0; nt < 6; ++nt)
#pragma unroll
      for (int kt = 0; kt < 8; ++kt)
        bfrag[nt][kt] = *(const short8*)(whh + (size_t)(n0 + nt * 16) * 256 + kt * 32 + kq);
  }

  float bhr = 0.f, bhz = 0.f, bhn = 0.f, hprev = 0.f;
  if (tid < 256) { bhr = bhh[tid]; bhz = bhh[256 + tid]; bhn = bhh[512 + tid]; }

  // prologue: wait DMA + h init, then converge
  asm volatile("s_waitcnt vmcnt(0) lgkmcnt(0)\n\ts_barrier" ::: "memory");

  for (int t = 0; t < Sd; ++t) {
    const int rb = t & 1, wb = rb ^ 1;

    // preload this step's gi values (buffer stable since prev barrier B;
    // DMA landing for the group was guaranteed at t%8==7 of the prev step)
    float gl0 = 0.f, gl1 = 0.f, gl2 = 0.f;
    if (tid < 256) {
      const float* gl = gi_lds[(t >> 3) & 1][t & 7];
      gl0 = gl[tid]; gl1 = gl[256 + tid]; gl2 = gl[512 + tid];
    }

    // --- MFMA phase (all 8 waves, 48 MFMAs each) ---
    f32x4 acc[6];
#pragma unroll
    for (int nt = 0; nt < 6; ++nt) acc[nt] = (f32x4){0.f, 0.f, 0.f, 0.f};
#pragma unroll
    for (int kt = 0; kt < 8; ++kt) {
      // broadcast h chunk; A rows 0-15 all replicate h (only D row 0 is read)
      short8 av = *(const short8*)(&h_bf[rb][kt * 32 + kq]);
#pragma unroll
      for (int nt = 0; nt < 6; ++nt)
        acc[nt] = __builtin_amdgcn_mfma_f32_16x16x32_bf16(av, bfrag[nt][kt], acc[nt], 0, 0, 0);
      __builtin_amdgcn_sched_group_barrier(0x100, 1, 0);  // DS_READ x1
      __builtin_amdgcn_sched_group_barrier(0x008, 6, 0);  // MFMA x6
    }
    if (lane < 16) {
#pragma unroll
      for (int nt = 0; nt < 6; ++nt) gh[w * 96 + nt * 16 + lane] = acc[nt][0];
    }
    asm volatile("s_waitcnt lgkmcnt(0)\n\ts_barrier" ::: "memory");   // barrier A: gh visible

    if (tid < 256) {
      // --- elementwise waves 0-3: one h value per lane ---
      float rr = fsigm(gl0 + gh[tid] + bhr);
      float zz = fsigm(gl1 + gh[256 + tid] + bhz);
      float nn = ftanh(gl2 + rr * (gh[512 + tid] + bhn));
      float hn = (1.f - zz) * nn + zz * hprev;
      hprev = hn;
      h_bf[wb][tid] = __float2bfloat16(hn);
      stg32[(t >> 3) & 1][t & 7][tid] = hn;
    } else if ((t & 7) == 0) {
      // --- memory waves 4-7: overlapped with elementwise ---
      if (t + 8 < Sd) {
        // prefetch tile t+8 into the buffer NOT read this group
        const int buf = ((t >> 3) + 1) & 1;
#pragma unroll
        for (int i = 0; i < 6; ++i) {
          int idx = (tid - 256) + i * 256;   // 0..1535
          int u = idx / 192;
          int c4 = (idx - u * 192) * 4;
          int s = dir ? (255 - (t + 8 + u)) : (t + 8 + u);
          const float* g = gi + (size_t)(((b << 8) + s) * 768 + c4);
          __builtin_amdgcn_global_load_lds(
              (const __attribute__((address_space(1))) unsigned int*)g,
              (__attribute__((address_space(3))) unsigned int*)&gi_lds[buf][u][c4], 16, 0, 0);
        }
      }
      if (t >= 8) {
        // store the group finished last step (steps t-8..t-1)
        const int base = t - 8;
        const int gp = ((t >> 3) - 1) & 1;
        const int d = tid - 256;
#pragma unroll
        for (int u = 0; u < 8; ++u) {
          int sg = dir ? (255 - (base + u)) : (base + u);
          size_t rowg = (size_t)((b << 8) + sg);
          int col = dir ? (256 + d) : d;
          float v = stg32[gp][u][d];
          sent_rep[rowg * 512 + col] = v;
          sent_rep_bf[rowg * 512 + col] = __float2bfloat16(v);
        }
      }
    }
    // memory waves: guarantee the NEXT group's tile (DMA'd at t-7) has landed
    // before barrier B of the group's last step -> step-top preload is safe.
    if (w >= 4 && (t & 7) == 7)
      asm volatile("s_waitcnt vmcnt(0)" ::: "memory");
    asm volatile("s_waitcnt lgkmcnt(0)\n\ts_barrier" ::: "memory");   // barrier B: h visible
  }

  // epilogue: store last group (31, in stg32[1]) + final hidden
  if (w >= 4) {
    const int base = 248, d = tid - 256;
#pragma unroll
    for (int u = 0; u < 8; ++u) {
      int sg = dir ? (255 - (base + u)) : (base + u);
      size_t rowg = (size_t)((b << 8) + sg);
      int col = dir ? (256 + d) : d;
      float v = stg32[1][u][d];
      sent_rep[rowg * 512 + col] = v;
      sent_rep_bf[rowg * 512 + col] = __float2bfloat16(v);
    }
  } else {
    (dir ? hT_b : hT_f)[b * 256 + tid] = hprev;
  }
}

// ---------------------------------------------------------------------------
// 5. FUSED topic_mat + doc_vec. block 256.
// blocks [0,512): topic boundary differencing (bt = blk)
// blocks [512,544): doc_vec torch view(B,2H) (b = blk-512, 2 elems/thread)
__global__ void dt_kernel(const int* __restrict__ tse, const float* __restrict__ sent_rep,
                          const float* __restrict__ hTf, const float* __restrict__ hTb,
                          __hip_bfloat16* __restrict__ topic_bf, __hip_bfloat16* __restrict__ dv) {
  const int blk = blockIdx.x;
  const int tid = threadIdx.x;
  if (blk < 512) {
    int bt = blk;
    int b = bt >> 4;
    int st = tse[bt * 2], en = tse[bt * 2 + 1];   // 1-indexed
    auto pad = [&](int i, int col) -> float {
      if (i < 1 || i > Sd) return 0.f;
      return sent_rep[((size_t)((b << 8) + (i - 1))) * 512 + col];
    };
    float fwd = pad(en, tid) - pad(st - 1, tid);
    float bwd = pad(st, Hd + tid) - pad(en + 1, Hd + tid);
    topic_bf[(size_t)bt * 512 + tid] = __float2bfloat16(fwd);
    topic_bf[(size_t)bt * 512 + Hd + tid] = __float2bfloat16(bwd);
    return;
  }
  const int b = blk - 512;
#pragma unroll
  for (int r = 0; r < 2; ++r) {
    int jj = tid + r * 256;
    int idx = b * 512 + jj;
    int dsel = idx >> 13;            // /8192
    int rem = idx & 8191;
    int bp = rem >> 8, hp = rem & 255;
    float v = (dsel ? hTb : hTf)[bp * Hd + hp];
    dv[idx] = __float2bfloat16(v);
  }
}

// ---------------------------------------------------------------------------
// 7. attention scores. grid 8192 (b*256+s), block 256.
__global__ void scores_kernel(const float* __restrict__ PD, const float* __restrict__ RT,
                              const float* __restrict__ QU, const float* __restrict__ v_att,
                              const int* __restrict__ tse,
                              float* __restrict__ dsc, float* __restrict__ tsc) {
  int r = blockIdx.x;
  int b = r >> 8, s = r & 255;
  int tid = threadIdx.x;
  int tsel = Td - 1;
  for (int t = 0; t < Td; ++t) {
    if (tse[(b * Td + t) * 2 + 1] >= s + 1) { tsel = t; break; }
  }
  const float* q = QU + (size_t)r * 1280;
  const float* p = PD + (size_t)b * 1280;
  const float* rr = RT + (size_t)(b * Td + tsel) * 1280;
  float accd = 0.f, acct = 0.f;
  for (int n = tid; n < 1024; n += 256) {
    float qv = q[n];
    float vv = v_att[n];
    accd += ftanh(p[n] + qv) * vv;
    acct += ftanh(rr[n] + qv) * vv;
  }
  __shared__ float s1[256], s2[256];
  s1[tid] = accd; s2[tid] = acct;
  __syncthreads();
  for (int off = 128; off > 0; off >>= 1) {
    if (tid < off) { s1[tid] += s1[tid + off]; s2[tid] += s2[tid + off]; }
    __syncthreads();
  }
  if (tid == 0) { dsc[r] = s1[0]; tsc[r] = s2[0]; }
}

// 8. softmax over s per batch (both score sets). grid 32, block 256.
__global__ void softmax_kernel(const float* __restrict__ dsc, const float* __restrict__ tsc,
                               float* __restrict__ dw, float* __restrict__ tw) {
  int b = blockIdx.x, s = threadIdx.x;
  __shared__ float red[256];
  for (int which = 0; which < 2; ++which) {
    const float* src = which ? tsc : dsc;
    float v = src[b * Sd + s];
    red[s] = v; __syncthreads();
    for (int off = 128; off > 0; off >>= 1) {
      if (s < off) red[s] = fmaxf(red[s], red[s + off]);
      __syncthreads();
    }
    float m = red[0]; __syncthreads();
    float e = __expf(v - m);
    red[s] = e; __syncthreads();
    for (int off = 128; off > 0; off >>= 1) {
      if (s < off) red[s] += red[s + off];
      __syncthreads();
    }
    float sum = red[0]; __syncthreads();
    (which ? tw : dw)[b * Sd + s] = e / sum;
  }
}

// 9. final head. grid 8192, block 256. OUTPUT IS FP32.
__global__ void final_kernel(const float* __restrict__ QU, const float* __restrict__ PD,
                             const float* __restrict__ RT, const float* __restrict__ dw,
                             const float* __restrict__ tw, const float* __restrict__ b_dna,
                             const float* __restrict__ w_out,
                             const float* __restrict__ b_out,
                             const int* __restrict__ tse, float* __restrict__ out) {
  int r = blockIdx.x;
  int b = r >> 8, s = r & 255;
  int dd = threadIdx.x;
  int tsel = Td - 1;
  for (int t = 0; t < Td; ++t) {
    if (tse[(b * Td + t) * 2 + 1] >= s + 1) { tsel = t; break; }
  }
  float wdv = dw[b * Sd + s], wtv = tw[b * Sd + s];
  float x = QU[(size_t)r * 1280 + 1024 + dd] + wdv * PD[(size_t)b * 1280 + 1024 + dd] +
            wtv * RT[(size_t)(b * Td + tsel) * 1280 + 1024 + dd] + b_dna[dd];
  x = fmaxf(x, 0.f);
  float term = x * w_out[dd];
  __shared__ float red[256];
  red[dd] = term; __syncthreads();
  for (int off = 128; off > 0; off >>= 1) {
    if (dd < off) red[dd] += red[dd + off];
    __syncthreads();
  }
  if (dd == 0) out[r] = red[0] + b_out[0];
}

// ---------------------------------------------------------------------------
extern "C" void kernel_launch(void* const* d_in, const int* in_sizes, int n_in,
                              void* d_out, int out_size, void* d_ws, size_t ws_size,
                              hipStream_t stream) {
  const int* word_ids = (const int*)d_in[0];
  const int* tse      = (const int*)d_in[1];
  const float* emb   = (const float*)d_in[2];
  const float* wih_f = (const float*)d_in[3];
  const float* whh_f = (const float*)d_in[4];
  const float* bih_f = (const float*)d_in[5];
  const float* bhh_f = (const float*)d_in[6];
  const float* wih_b = (const float*)d_in[7];
  const float* whh_b = (const float*)d_in[8];
  const float* bih_b = (const float*)d_in[9];
  const float* bhh_b = (const float*)d_in[10];
  const float* w_att = (const float*)d_in[11];
  const float* v_att = (const float*)d_in[12];
  const float* w_dna = (const float*)d_in[13];
  const float* b_dna = (const float*)d_in[14];
  const float* w_out = (const float*)d_in[15];
  const float* b_out = (const float*)d_in[16];
  float* out = (float*)d_out;
  char* ws = (char*)d_ws;

  const int M = Bd * Sd;  // 8192

  // workspace layout (bytes)
  size_t off = 0;
  auto alloc = [&](size_t sz) { size_t o = off; off += (sz + 255) & ~(size_t)255; return o; };
  size_t o_svbf   = alloc((size_t)M * EP * 2);          // A_pad bf16 [8192,320]
  size_t o_wpad   = alloc((size_t)2 * 768 * EP * 2);    // wih pad f+b, ADJACENT
  size_t o_whhbf  = alloc((size_t)768 * Hd * 2 * 2);    // whh f+b bf16
  size_t o_wpack1 = alloc((size_t)1280 * 512 * 2);      // [W_att[:512];W_dna[512:]] ^T bf16
  size_t o_wpack2 = alloc((size_t)1280 * 512 * 2);      // [W_att[512:];W_dna[:512]] ^T bf16
  size_t o_bcat   = alloc((size_t)1536 * 4);            // bih_f|bih_b fp32
  size_t o_hTf    = alloc((size_t)Bd * Hd * 4);
  size_t o_hTb    = alloc((size_t)Bd * Hd * 4);
  size_t o_dvbf   = alloc((size_t)Bd * 512 * 2);        // doc_vec bf16
  size_t o_topbf  = alloc((size_t)Bd * Td * 512 * 2);   // topic_mat bf16
  size_t o_PD     = alloc((size_t)Bd * 1280 * 4);       // [P | dvd]
  size_t o_RT     = alloc((size_t)Bd * Td * 1280 * 4);  // [R | tvd]
  size_t o_dsc    = alloc((size_t)Bd * Sd * 4);
  size_t o_tsc    = alloc((size_t)Bd * Sd * 4);
  size_t o_dw     = alloc((size_t)Bd * Sd * 4);
  size_t o_tw     = alloc((size_t)Bd * Sd * 4);
  size_t o_srep32 = alloc((size_t)M * 512 * 4);         // sent_rep fp32
  size_t o_srepbf = alloc((size_t)M * 512 * 2);         // sent_rep bf16
  size_t o_gif    = alloc((size_t)M * 768 * 4);         // gi fwd fp32 (contiguous)
  size_t o_gib    = alloc((size_t)M * 768 * 4);         // gi bwd fp32 (contiguous)
  // QU [8192,1280] f32 overlays the dead gif+gib region after the GRU
  size_t o_QU = o_gif;
  (void)ws_size;

  __hip_bfloat16* svbf   = (__hip_bfloat16*)(ws + o_svbf);
  __hip_bfloat16* wpadf  = (__hip_bfloat16*)(ws + o_wpad);
  __hip_bfloat16* wpadb  = wpadf + 768 * EP;
  __hip_bfloat16* whhbf_f = (__hip_bfloat16*)(ws + o_whhbf);
  __hip_bfloat16* whhbf_b = whhbf_f + 768 * Hd;
  __hip_bfloat16* wpack1 = (__hip_bfloat16*)(ws + o_wpack1);
  __hip_bfloat16* wpack2 = (__hip_bfloat16*)(ws + o_wpack2);
  float* bcat = (float*)(ws + o_bcat);
  float* hTf = (float*)(ws + o_hTf);
  float* hTb = (float*)(ws + o_hTb);
  __hip_bfloat16* dvbf  = (__hip_bfloat16*)(ws + o_dvbf);
  __hip_bfloat16* topbf = (__hip_bfloat16*)(ws + o_topbf);
  float* PD  = (float*)(ws + o_PD);
  float* RT  = (float*)(ws + o_RT);
  float* dsc = (float*)(ws + o_dsc);
  float* tsc = (float*)(ws + o_tsc);
  float* dw  = (float*)(ws + o_dw);
  float* tw  = (float*)(ws + o_tw);
  float* srep32 = (float*)(ws + o_srep32);
  __hip_bfloat16* srepbf = (__hip_bfloat16*)(ws + o_srepbf);
  float* gif = (float*)(ws + o_gif);
  float* gib = (float*)(ws + o_gib);
  float* QU  = (float*)(ws + o_QU);

  // 1. fused: sentence means + weight prep + bias concat
  sentprep_kernel<<<10962, 320, 0, stream>>>(word_ids, emb, svbf,
                                             wih_f, wih_b, whh_f, whh_b,
                                             wpadf, wpadb, whhbf_f, whhbf_b,
                                             bih_f, bih_b, bcat);
  // 2. fused input projection, split epilogue -> contiguous gif/gib
  {
    dim3 grid(M / 128, 1536 / 128);
    gemm_gi_kernel<<<grid, 256, 0, stream>>>(svbf, wpadf, gif, gib, bcat);
  }
  // 3. GRU recurrence + fused att/dna weight packing on idle CUs
  gru_mfma_kernel<<<384, 512, 0, stream>>>(gif, gib, whhbf_f, whhbf_b, bhh_f, bhh_b,
                                           srep32, srepbf, hTf, hTb,
                                           w_att, w_dna, wpack1, wpack2);
  // 4. fused topic_mat + doc_vec
  dt_kernel<<<544, 256, 0, stream>>>(tse, srep32, hTf, hTb, topbf, dvbf);
  // 5. merged QU+RT+PD GEMMs (one launch, 690 blocks)
  gemm3_kernel<<<690, 256, 0, stream>>>(srepbf, topbf, dvbf, wpack1, wpack2, QU, RT, PD);
  // 6. scores + softmax
  scores_kernel<<<M, 256, 0, stream>>>(PD, RT, QU, v_att, tse, dsc, tsc);
  softmax_kernel<<<Bd, 256, 0, stream>>>(dsc, tsc, dw, tw);
  // 7. fused dense head -> logits (fp32)
  final_kernel<<<M, 256, 0, stream>>>(QU, PD, RT, dw, tw, b_dna, w_out, b_out, tse, out);
}